// Round 1
// baseline (1102.475 us; speedup 1.0000x reference)
//
#include <hip/hip_runtime.h>
#include <math.h>

#define C_DIM 64
#define CQ    8
#define BATCH 2
#define NVOX  8000      // 20*20*20
#define MT    64        // queries per block
#define NT    64        // keys per tile

// ---------------------------------------------------------------------------
// Kernel 1: per-voxel 1x1x1 conv projections q,k,v
//   x: [B, C, N] (n contiguous) -> q,k: [B, N, 8] AoS ; v: [B, N, 64] AoS
// ---------------------------------------------------------------------------
__global__ __launch_bounds__(256) void qkv_kernel(
    const float* __restrict__ x,
    const float* __restrict__ wq, const float* __restrict__ bq,
    const float* __restrict__ wk, const float* __restrict__ bk,
    const float* __restrict__ wv, const float* __restrict__ bv,
    float* __restrict__ qws, float* __restrict__ kws, float* __restrict__ vws)
{
    int tid = blockIdx.x * blockDim.x + threadIdx.x;
    if (tid >= BATCH * NVOX) return;
    int b = tid / NVOX;
    int n = tid - b * NVOX;
    const float* xp = x + (size_t)b * C_DIM * NVOX + n;

    float qa[CQ], ka[CQ], va[C_DIM];
#pragma unroll
    for (int i = 0; i < CQ; ++i) { qa[i] = bq[i]; ka[i] = bk[i]; }
#pragma unroll
    for (int i = 0; i < C_DIM; ++i) va[i] = bv[i];

    for (int c = 0; c < C_DIM; ++c) {
        float xc = xp[(size_t)c * NVOX];   // coalesced across threads (n = lane)
#pragma unroll
        for (int i = 0; i < CQ; ++i) {
            qa[i] = fmaf(wq[i * C_DIM + c], xc, qa[i]);
            ka[i] = fmaf(wk[i * C_DIM + c], xc, ka[i]);
        }
#pragma unroll
        for (int i = 0; i < C_DIM; ++i)
            va[i] = fmaf(wv[i * C_DIM + c], xc, va[i]);
    }

    float4* qo = (float4*)(qws + (size_t)tid * CQ);
    qo[0] = make_float4(qa[0], qa[1], qa[2], qa[3]);
    qo[1] = make_float4(qa[4], qa[5], qa[6], qa[7]);
    float4* ko = (float4*)(kws + (size_t)tid * CQ);
    ko[0] = make_float4(ka[0], ka[1], ka[2], ka[3]);
    ko[1] = make_float4(ka[4], ka[5], ka[6], ka[7]);
    float4* vo = (float4*)(vws + (size_t)tid * C_DIM);
#pragma unroll
    for (int i = 0; i < 16; ++i)
        vo[i] = make_float4(va[4*i], va[4*i+1], va[4*i+2], va[4*i+3]);
}

// ---------------------------------------------------------------------------
// Kernel 2: flash attention over N=8000 keys, 64 queries per block.
//   grid = B * (N/MT) = 250 blocks, 256 threads.
//   Phases per key-tile: stage K/V -> energies -> online softmax -> accumulate
// ---------------------------------------------------------------------------
__global__ __launch_bounds__(256) void attn_kernel(
    const float* __restrict__ qws, const float* __restrict__ kws,
    const float* __restrict__ vws, const float* __restrict__ x,
    const float* __restrict__ gamma, float* __restrict__ out)
{
    __shared__ __align__(16) float k_lds[NT][CQ];       // 2 KB  [nj][cq]
    __shared__ __align__(16) float v_lds[NT][C_DIM];    // 16 KB [nj][c]
    __shared__ __align__(16) float p_lds[NT][MT];       // 16 KB [nj][qi] (e then p)
    __shared__ float m_arr[MT], l_arr[MT], alpha_arr[MT];

    const int blk = blockIdx.x;                 // 0..249
    const int b   = blk / (NVOX / MT);
    const int m0  = (blk % (NVOX / MT)) * MT;
    const int t   = threadIdx.x;

    // energy-phase mapping: thread owns query e_qi, 16 keys starting at e_njg*16
    const int e_qi  = t & 63;
    const int e_njg = t >> 6;                   // 0..3
    // accumulate-phase mapping: 4 queries x 4 channels per thread
    const int a_qg = t >> 4;                    // 0..15 -> queries a_qg*4..+3
    const int a_cg = t & 15;                    // 0..15 -> channels a_cg*4..+3

    // load this thread's query vector (once per block)
    const float4* qp = (const float4*)(qws + ((size_t)b * NVOX + m0 + e_qi) * CQ);
    const float4 qr0 = qp[0];
    const float4 qr1 = qp[1];

    if (t < MT) { m_arr[t] = -1e30f; l_arr[t] = 0.0f; }

    float acc[4][4];
#pragma unroll
    for (int i = 0; i < 4; ++i)
#pragma unroll
        for (int j = 0; j < 4; ++j) acc[i][j] = 0.0f;

    const float4* kbase = (const float4*)(kws + ((size_t)b * NVOX) * CQ);
    const float4* vbase = (const float4*)(vws + ((size_t)b * NVOX) * C_DIM);

    for (int tile = 0; tile < NVOX / NT; ++tile) {
        const int n0 = tile * NT;

        // ---- stage K (512 floats) and V (4096 floats) into LDS ----
        if (t < 128)
            ((float4*)k_lds)[t] = kbase[(size_t)n0 * (CQ / 4) + t];
#pragma unroll
        for (int j = 0; j < 4; ++j) {
            int idx = t + j * 256;              // 0..1023 float4 slots
            ((float4*)v_lds)[idx] = vbase[(size_t)n0 * (C_DIM / 4) + idx];
        }
        __syncthreads();

        // ---- energies: e[nj][qi] = q_qi . k_nj ----
#pragma unroll
        for (int j = 0; j < 16; ++j) {
            int nj = e_njg * 16 + j;
            float4 k0 = *(const float4*)&k_lds[nj][0];
            float4 k1 = *(const float4*)&k_lds[nj][4];
            float e = qr0.x * k0.x + qr0.y * k0.y + qr0.z * k0.z + qr0.w * k0.w
                    + qr1.x * k1.x + qr1.y * k1.y + qr1.z * k1.z + qr1.w * k1.w;
            p_lds[nj][e_qi] = e;
        }
        __syncthreads();

        // ---- online softmax update (one thread per query) ----
        if (t < MT) {
            float mo = m_arr[t];
            float tm = mo;
#pragma unroll 8
            for (int nj = 0; nj < NT; ++nj) tm = fmaxf(tm, p_lds[nj][t]);
            float alpha = __expf(mo - tm);
            float s = 0.0f;
#pragma unroll 8
            for (int nj = 0; nj < NT; ++nj) {
                float p = __expf(p_lds[nj][t] - tm);
                p_lds[nj][t] = p;
                s += p;
            }
            m_arr[t] = tm;
            l_arr[t] = l_arr[t] * alpha + s;
            alpha_arr[t] = alpha;
        }
        __syncthreads();

        // ---- accumulate: acc[q][c] = alpha*acc + sum_nj p[nj][q]*v[nj][c] ----
        {
            const int qbase = a_qg * 4;
            const int cbase = a_cg * 4;
            float4 al = *(const float4*)&alpha_arr[qbase];
#pragma unroll
            for (int j = 0; j < 4; ++j) {
                acc[0][j] *= al.x; acc[1][j] *= al.y;
                acc[2][j] *= al.z; acc[3][j] *= al.w;
            }
#pragma unroll 4
            for (int nj = 0; nj < NT; ++nj) {
                float4 pv = *(const float4*)&p_lds[nj][qbase];
                float4 vv = *(const float4*)&v_lds[nj][cbase];
                acc[0][0] = fmaf(pv.x, vv.x, acc[0][0]);
                acc[0][1] = fmaf(pv.x, vv.y, acc[0][1]);
                acc[0][2] = fmaf(pv.x, vv.z, acc[0][2]);
                acc[0][3] = fmaf(pv.x, vv.w, acc[0][3]);
                acc[1][0] = fmaf(pv.y, vv.x, acc[1][0]);
                acc[1][1] = fmaf(pv.y, vv.y, acc[1][1]);
                acc[1][2] = fmaf(pv.y, vv.z, acc[1][2]);
                acc[1][3] = fmaf(pv.y, vv.w, acc[1][3]);
                acc[2][0] = fmaf(pv.z, vv.x, acc[2][0]);
                acc[2][1] = fmaf(pv.z, vv.y, acc[2][1]);
                acc[2][2] = fmaf(pv.z, vv.z, acc[2][2]);
                acc[2][3] = fmaf(pv.z, vv.w, acc[2][3]);
                acc[3][0] = fmaf(pv.w, vv.x, acc[3][0]);
                acc[3][1] = fmaf(pv.w, vv.y, acc[3][1]);
                acc[3][2] = fmaf(pv.w, vv.z, acc[3][2]);
                acc[3][3] = fmaf(pv.w, vv.w, acc[3][3]);
            }
        }
        __syncthreads();   // protect LDS before next tile overwrites
    }

    // ---- epilogue: out = gamma * acc/l + x ----
    const float g = gamma[0];
#pragma unroll
    for (int i = 0; i < 4; ++i) {
        int q = a_qg * 4 + i;
        float invl = 1.0f / l_arr[q];
#pragma unroll
        for (int j = 0; j < 4; ++j) {
            int c = a_cg * 4 + j;
            size_t xi = (size_t)b * C_DIM * NVOX + (size_t)c * NVOX + (m0 + q);
            out[xi] = g * (acc[i][j] * invl) + x[xi];
        }
    }
}

// ---------------------------------------------------------------------------
extern "C" void kernel_launch(void* const* d_in, const int* in_sizes, int n_in,
                              void* d_out, int out_size, void* d_ws, size_t ws_size,
                              hipStream_t stream) {
    const float* x     = (const float*)d_in[0];
    const float* wq    = (const float*)d_in[1];
    const float* bq    = (const float*)d_in[2];
    const float* wk    = (const float*)d_in[3];
    const float* bk    = (const float*)d_in[4];
    const float* wv    = (const float*)d_in[5];
    const float* bv    = (const float*)d_in[6];
    const float* gamma = (const float*)d_in[7];
    float* out = (float*)d_out;

    float* ws  = (float*)d_ws;
    float* qws = ws;                              // [B,N,8]   = 128000 floats
    float* kws = ws + (size_t)BATCH * NVOX * CQ;  // [B,N,8]   = 128000 floats
    float* vws = kws + (size_t)BATCH * NVOX * CQ; // [B,N,64]  = 1024000 floats

    int total = BATCH * NVOX;
    qkv_kernel<<<(total + 255) / 256, 256, 0, stream>>>(
        x, wq, bq, wk, bk, wv, bv, qws, kws, vws);

    attn_kernel<<<BATCH * (NVOX / MT), 256, 0, stream>>>(
        qws, kws, vws, x, gamma, out);
}

// Round 2
// 242.584 us; speedup vs baseline: 4.5447x; 4.5447x over previous
//
#include <hip/hip_runtime.h>
#include <math.h>

#define C_DIM 64
#define CQ    8
#define BATCH 2
#define NVOX  8000          // 20*20*20
#define MT    32            // queries per block
#define NT    64            // keys per tile
#define NTILES (NVOX / NT)  // 125
#define QTILES (NVOX / MT)  // 250
#define VSTRIDE 72          // bf16 elems per v_lds row (64 + 8 pad, keeps 16B align)
#define PSTRIDE 72

typedef float  f32x16 __attribute__((ext_vector_type(16)));
typedef __bf16 bf16x8 __attribute__((ext_vector_type(8)));
typedef unsigned short u16x8 __attribute__((ext_vector_type(8)));

__device__ __forceinline__ unsigned short f2bf(float f) {
    unsigned int u = __float_as_uint(f);
    u += 0x7fff + ((u >> 16) & 1);      // round-to-nearest-even
    return (unsigned short)(u >> 16);
}

// ---------------------------------------------------------------------------
// Kernel 1: 1x1x1 conv projections.
//   q,k: fp32 AoS [b][n][8];  v: bf16 planar [b][c][n] (ready for [c][key] LDS tiles)
// ---------------------------------------------------------------------------
__global__ __launch_bounds__(128) void qkv_kernel(
    const float* __restrict__ x,
    const float* __restrict__ wq, const float* __restrict__ bq,
    const float* __restrict__ wk, const float* __restrict__ bk,
    const float* __restrict__ wv, const float* __restrict__ bv,
    float* __restrict__ qws, float* __restrict__ kws,
    unsigned short* __restrict__ vws)
{
    int tid = blockIdx.x * blockDim.x + threadIdx.x;   // 0..15999
    int b = tid / NVOX;
    int n = tid - b * NVOX;
    const float* xp = x + (size_t)b * C_DIM * NVOX + n;

    float qa[CQ], ka[CQ], va[C_DIM];
#pragma unroll
    for (int i = 0; i < CQ; ++i) { qa[i] = bq[i]; ka[i] = bk[i]; }
#pragma unroll
    for (int i = 0; i < C_DIM; ++i) va[i] = bv[i];

    for (int c = 0; c < C_DIM; ++c) {
        float xc = xp[(size_t)c * NVOX];               // coalesced
#pragma unroll
        for (int i = 0; i < CQ; ++i) {
            qa[i] = fmaf(wq[i * C_DIM + c], xc, qa[i]);
            ka[i] = fmaf(wk[i * C_DIM + c], xc, ka[i]);
        }
#pragma unroll
        for (int i = 0; i < C_DIM; ++i)
            va[i] = fmaf(wv[i * C_DIM + c], xc, va[i]);
    }

    float4* qo = (float4*)(qws + (size_t)tid * CQ);
    qo[0] = make_float4(qa[0], qa[1], qa[2], qa[3]);
    qo[1] = make_float4(qa[4], qa[5], qa[6], qa[7]);
    float4* ko = (float4*)(kws + (size_t)tid * CQ);
    ko[0] = make_float4(ka[0], ka[1], ka[2], ka[3]);
    ko[1] = make_float4(ka[4], ka[5], ka[6], ka[7]);
#pragma unroll
    for (int c = 0; c < C_DIM; ++c)                    // coalesced 2B stores per c
        vws[((size_t)b * C_DIM + c) * NVOX + n] = f2bf(va[c]);
}

// ---------------------------------------------------------------------------
// Kernel 2: flash attention. grid = B*(N/MT) = 500 blocks, 256 threads.
//   Waves: (chalf = w&1, khalf = w>>1). PV via mfma_f32_32x32x16_bf16.
//   Softmax: thread owns (q = (t&7)+8*wave, 8 keys of group g=(t>>3)&7);
//   m,l replicated in regs, reduced via shfl_xor(8,16,32).
// ---------------------------------------------------------------------------
__global__ __launch_bounds__(256, 2) void attn_kernel(
    const float* __restrict__ qws, const float* __restrict__ kws,
    const unsigned short* __restrict__ vws, const float* __restrict__ x,
    const float* __restrict__ gamma, float* __restrict__ out)
{
    __shared__ __align__(16) float k_lds[NT][CQ];                  // 2 KB
    __shared__ __align__(16) unsigned short v_lds[C_DIM][VSTRIDE]; // 9216 B [c][key]
    __shared__ __align__(16) unsigned short pT[MT][PSTRIDE];       // 4608 B [q][key]
    __shared__ __align__(16) float alpha_arr[MT];
    __shared__ __align__(16) float l_arr[MT];
    __shared__ __align__(16) float comb[2][64][16];                // 8 KB

    const int blk  = blockIdx.x;
    const int b    = blk / QTILES;
    const int m0   = (blk % QTILES) * MT;
    const int t    = threadIdx.x;
    const int lane = t & 63;
    const int wave = t >> 6;
    const int h    = lane >> 5;

    // softmax/energy mapping
    const int eq = (t & 7) + 8 * wave;   // query 0..31 (8 per wave)
    const int eg = (t >> 3) & 7;         // key-group 0..7 (all in one wave per q)

    // mfma mapping
    const int chalf = wave & 1;
    const int khalf = wave >> 1;
    const int mrow  = lane & 31;

    // V staging mapping: 4 threads per channel row
    const int vc = t >> 2;               // channel 0..63
    const int vp = t & 3;                // 32B chunk

    // per-thread query vector (fp32)
    const float4* qp = (const float4*)(qws + ((size_t)b * NVOX + m0 + eq) * CQ);
    const float4 q0 = qp[0];
    const float4 q1 = qp[1];

    float m_run = -1e30f, l_run = 0.0f;
    f32x16 acc;
#pragma unroll
    for (int i = 0; i < 16; ++i) acc[i] = 0.0f;

    const float4* kbase = (const float4*)(kws + (size_t)b * NVOX * CQ);
    const unsigned short* vbase = vws + ((size_t)b * C_DIM + vc) * NVOX;

    uint4 vreg0, vreg1;
    float4 kreg;
    {   // prefetch tile 0
        const uint4* vsrc = (const uint4*)(vbase);
        vreg0 = vsrc[vp * 2];
        vreg1 = vsrc[vp * 2 + 1];
        if (t < 128) kreg = kbase[t];
    }

    for (int tile = 0; tile < NTILES; ++tile) {
        __syncthreads();                        // prev MFMA done reading v/pT
        *(uint4*)&v_lds[vc][vp * 16]     = vreg0;
        *(uint4*)&v_lds[vc][vp * 16 + 8] = vreg1;
        if (t < 128) ((float4*)k_lds)[t] = kreg;
        __syncthreads();                        // tiles staged

        if (tile + 1 < NTILES) {                // prefetch next tile (latency hidden)
            int n0 = (tile + 1) * NT;
            const uint4* vsrc = (const uint4*)(vbase + n0);
            vreg0 = vsrc[vp * 2];
            vreg1 = vsrc[vp * 2 + 1];
            if (t < 128) kreg = kbase[n0 * 2 + t];
        }

        // ---- energies (fp32 VALU), j-loop rotated by eg to dodge LDS bank conflicts
        float e[8];
#pragma unroll
        for (int j = 0; j < 8; ++j) {
            int je = (j + eg) & 7;
            int r  = eg * 8 + je;
            float4 ka = *(const float4*)&k_lds[r][0];
            float4 kb = *(const float4*)&k_lds[r][4];
            e[j] = q0.x * ka.x + q0.y * ka.y + q0.z * ka.z + q0.w * ka.w
                 + q1.x * kb.x + q1.y * kb.y + q1.z * kb.z + q1.w * kb.w;
        }

        // ---- online softmax, in-register (8 g-copies of each q live in one wave)
        float tm = e[0];
#pragma unroll
        for (int j = 1; j < 8; ++j) tm = fmaxf(tm, e[j]);
        tm = fmaxf(tm, __shfl_xor(tm, 8, 64));
        tm = fmaxf(tm, __shfl_xor(tm, 16, 64));
        tm = fmaxf(tm, __shfl_xor(tm, 32, 64));
        float mnew  = fmaxf(m_run, tm);
        float alpha = __expf(m_run - mnew);
        m_run = mnew;

        float s = 0.0f;
#pragma unroll
        for (int j = 0; j < 8; ++j) {
            int je = (j + eg) & 7;
            float p = __expf(e[j] - mnew);
            s += p;
            pT[eq][eg * 8 + je] = f2bf(p);
        }
        s += __shfl_xor(s, 8, 64);
        s += __shfl_xor(s, 16, 64);
        s += __shfl_xor(s, 32, 64);
        l_run = l_run * alpha + s;
        if (eg == 0) alpha_arr[eq] = alpha;
        __syncthreads();                        // pT/alpha ready

        // ---- rescale acc rows by alpha, then PV MFMA over this wave's key-half
#pragma unroll
        for (int r2 = 0; r2 < 4; ++r2) {
            float4 av = *(const float4*)&alpha_arr[8 * r2 + 4 * h];
            acc[4 * r2 + 0] *= av.x;
            acc[4 * r2 + 1] *= av.y;
            acc[4 * r2 + 2] *= av.z;
            acc[4 * r2 + 3] *= av.w;
        }
#pragma unroll
        for (int s2 = 0; s2 < 2; ++s2) {
            int k0 = khalf * 32 + s2 * 16 + h * 8;
            bf16x8 af = __builtin_bit_cast(bf16x8, *(const u16x8*)&pT[mrow][k0]);
            bf16x8 bf = __builtin_bit_cast(bf16x8,
                          *(const u16x8*)&v_lds[chalf * 32 + mrow][k0]);
            acc = __builtin_amdgcn_mfma_f32_32x32x16_bf16(af, bf, acc, 0, 0, 0);
        }
    }

    // ---- epilogue: combine key-halves, normalize, residual, store
    if (eg == 0) l_arr[eq] = l_run;
    __syncthreads();
    if (wave >= 2) {
#pragma unroll
        for (int i = 0; i < 16; ++i) comb[wave - 2][lane][i] = acc[i];
    }
    __syncthreads();
    if (wave < 2) {
        const float g = gamma[0];
#pragma unroll
        for (int i = 0; i < 16; ++i) acc[i] += comb[wave][lane][i];
        const int c = chalf * 32 + mrow;
#pragma unroll
        for (int r2 = 0; r2 < 4; ++r2) {
            float4 lv = *(const float4*)&l_arr[8 * r2 + 4 * h];
            int n = m0 + 8 * r2 + 4 * h;
            size_t idx = ((size_t)(b * C_DIM + c)) * NVOX + n;
            float4 xv = *(const float4*)&x[idx];
            float4 o;
            o.x = g * (acc[4 * r2 + 0] / lv.x) + xv.x;
            o.y = g * (acc[4 * r2 + 1] / lv.y) + xv.y;
            o.z = g * (acc[4 * r2 + 2] / lv.z) + xv.z;
            o.w = g * (acc[4 * r2 + 3] / lv.w) + xv.w;
            *(float4*)&out[idx] = o;
        }
    }
}

// ---------------------------------------------------------------------------
extern "C" void kernel_launch(void* const* d_in, const int* in_sizes, int n_in,
                              void* d_out, int out_size, void* d_ws, size_t ws_size,
                              hipStream_t stream) {
    const float* x     = (const float*)d_in[0];
    const float* wq    = (const float*)d_in[1];
    const float* bq    = (const float*)d_in[2];
    const float* wk    = (const float*)d_in[3];
    const float* bk    = (const float*)d_in[4];
    const float* wv    = (const float*)d_in[5];
    const float* bv    = (const float*)d_in[6];
    const float* gamma = (const float*)d_in[7];
    float* out = (float*)d_out;

    float* ws  = (float*)d_ws;
    float* qws = ws;                               // [B,N,8] fp32
    float* kws = ws + (size_t)BATCH * NVOX * CQ;   // [B,N,8] fp32
    unsigned short* vws = (unsigned short*)(kws + (size_t)BATCH * NVOX * CQ); // [B,C,N] bf16

    qkv_kernel<<<(BATCH * NVOX) / 128, 128, 0, stream>>>(
        x, wq, bq, wk, bk, wv, bv, qws, kws, vws);

    attn_kernel<<<BATCH * QTILES, 256, 0, stream>>>(
        qws, kws, vws, x, gamma, out);
}